// Round 3
// baseline (148.984 us; speedup 1.0000x reference)
//
#include <hip/hip_runtime.h>
#include <math.h>

// GTNormalLoss: kNN(k=10) PCA normals + cosine loss vs gt, mean over 8x4096 points.
// Round 3: counting-sort each batch by x into 256 bins (ws scratch), then each wave
// scans only the x-window that can contain its queries' true 10-NN (exact pruning
// via (dx)^2 > conservative upper bound of current 10th distance). 4 waves/block
// split the scan {left,right} x {even,odd bins}; exact merge of partial top-10s.

#define NPTS    4096
#define KNN     10
#define NBINS   256
#define XLO     (-5.5f)
#define BINW    (11.0f / 256.0f)
#define INVBW   (256.0f / 11.0f)
#define SCAN_BLOCKS 512          // 8 batches * 64 chunks of 64 queries

__device__ __forceinline__ unsigned int umed3(unsigned int a, unsigned int b, unsigned int c) {
    unsigned int r;
    asm("v_med3_u32 %0, %1, %2, %3" : "=v"(r) : "v"(a), "v"(b), "v"(c));
    return r;
}

// insert key into ascending sorted nd[0..9], dropping old max; all static indexing.
__device__ __forceinline__ void sift(unsigned int nd[KNN], unsigned int key) {
#pragma unroll
    for (int t = KNN - 1; t >= 1; --t)
        nd[t] = umed3(key, nd[t - 1], nd[t]);
    nd[0] = nd[0] < key ? nd[0] : key;
}

// ---- shared epilogue: covariance -> smallest eigenvector -> 1-cos loss ----
__device__ float normal_loss(const float4* pts, const unsigned int nd[KNN],
                             const float* g3)
{
    float nbx[KNN], nby[KNN], nbz[KNN];
    float sx = 0.f, sy = 0.f, sz = 0.f;
#pragma unroll
    for (int t = 0; t < KNN; ++t) {
        float4 pn = pts[nd[t] & 0xFFFu];
        nbx[t] = pn.x; nby[t] = pn.y; nbz[t] = pn.z;
        sx += pn.x; sy += pn.y; sz += pn.z;
    }
    float mx = sx / 10.0f, my = sy / 10.0f, mz = sz / 10.0f;
    float c00 = 0.f, c01 = 0.f, c02 = 0.f, c11 = 0.f, c12 = 0.f, c22 = 0.f;
#pragma unroll
    for (int t = 0; t < KNN; ++t) {
        float ux = nbx[t] - mx, uy = nby[t] - my, uz = nbz[t] - mz;
        c00 = fmaf(ux, ux, c00);
        c01 = fmaf(ux, uy, c01);
        c02 = fmaf(ux, uz, c02);
        c11 = fmaf(uy, uy, c11);
        c12 = fmaf(uy, uz, c12);
        c22 = fmaf(uz, uz, c22);
    }
    double a00 = (double)(c00 / 10.0f), a01 = (double)(c01 / 10.0f);
    double a02 = (double)(c02 / 10.0f), a11 = (double)(c11 / 10.0f);
    double a12 = (double)(c12 / 10.0f), a22 = (double)(c22 / 10.0f);

    double vx = 1.0, vy = 0.0, vz = 0.0;
    double qd = (a00 + a11 + a22) / 3.0;
    double p1 = a01 * a01 + a02 * a02 + a12 * a12;
    double b00 = a00 - qd, b11 = a11 - qd, b22 = a22 - qd;
    double p2 = b00 * b00 + b11 * b11 + b22 * b22 + 2.0 * p1;
    if (p2 > 1e-300) {
        double p = sqrt(p2 / 6.0);
        double inv = 1.0 / p;
        double m00 = b00 * inv, m01 = a01 * inv, m02 = a02 * inv;
        double m11 = b11 * inv, m12 = a12 * inv, m22 = b22 * inv;
        double detB = m00 * (m11 * m22 - m12 * m12)
                    - m01 * (m01 * m22 - m12 * m02)
                    + m02 * (m01 * m12 - m11 * m02);
        double r = 0.5 * detB;
        r = r < -1.0 ? -1.0 : (r > 1.0 ? 1.0 : r);
        double phi = acos(r) / 3.0;
        double eig0 = qd + 2.0 * p * cos(phi + 2.0943951023931953); // smallest
        double r0x = a00 - eig0, r0y = a01, r0z = a02;
        double r1y = a11 - eig0, r1z = a12;
        double r2z = a22 - eig0;
        double c0x = r0y * r1z - r0z * r1y;
        double c0y = r0z * r0y - r0x * r1z;
        double c0z = r0x * r1y - r0y * r0y;
        double c1x = r0y * r2z - r0z * r1z;
        double c1y = r0z * r0z - r0x * r2z;
        double c1z = r0x * r1z - r0y * r0z;
        double c2x = r1y * r2z - r1z * r1z;
        double c2y = r1z * r0z - r0y * r2z;
        double c2z = r0y * r1z - r1y * r0z;
        double n0 = c0x * c0x + c0y * c0y + c0z * c0z;
        double n1 = c1x * c1x + c1y * c1y + c1z * c1z;
        double n2 = c2x * c2x + c2y * c2y + c2z * c2z;
        double bx, by, bz, bn;
        if (n0 >= n1 && n0 >= n2) { bx = c0x; by = c0y; bz = c0z; bn = n0; }
        else if (n1 >= n2)        { bx = c1x; by = c1y; bz = c1z; bn = n1; }
        else                      { bx = c2x; by = c2y; bz = c2z; bn = n2; }
        if (bn > 1e-300) {
            double s = 1.0 / sqrt(bn);
            vx = bx * s; vy = by * s; vz = bz * s;
        }
    }
    float nx = (float)vx, ny = (float)vy, nz = (float)vz;
    float gx = g3[0], gy = g3[1], gz = g3[2];
    float dotg = nx * gx + ny * gy + nz * gz;
    float na = sqrtf(nx * nx + ny * ny + nz * nz);
    float gn = sqrtf(gx * gx + gy * gy + gz * gz);
    float cs = dotg / (fmaxf(na, 1e-8f) * fmaxf(gn, 1e-8f));
    return 1.0f - cs;
}

// ---- kernel 1: counting-sort each batch's points into 256 x-bins ----
__global__ __launch_bounds__(256) void gtnl_bin(
    const float* __restrict__ pred, float4* __restrict__ wsPts,
    unsigned int* __restrict__ wsBins)
{
    __shared__ unsigned int hist[NBINS];
    __shared__ unsigned int bst[NBINS + 1];

    const int tid = threadIdx.x;
    const int b   = blockIdx.x;
    const float* src = pred + (size_t)b * NPTS * 3;

    hist[tid] = 0;
    __syncthreads();

    float px[16], py[16], pz[16];
    int   pb[16], pidx[16];
#pragma unroll
    for (int k = 0; k < 16; ++k) {
        int p = tid + 256 * k;
        float x = src[3 * p + 0];
        float y = src[3 * p + 1];
        float z = src[3 * p + 2];
        int bin = (int)floorf((x - XLO) * INVBW);
        bin = bin < 0 ? 0 : (bin > NBINS - 1 ? NBINS - 1 : bin);
        px[k] = x; py[k] = y; pz[k] = z; pb[k] = bin; pidx[k] = p;
        atomicAdd(&hist[bin], 1u);
    }
    __syncthreads();

    if (tid < 64) {
        unsigned s0 = hist[4 * tid + 0], s1 = hist[4 * tid + 1];
        unsigned s2 = hist[4 * tid + 2], s3 = hist[4 * tid + 3];
        unsigned tot = s0 + s1 + s2 + s3;
        unsigned pre = tot;
#pragma unroll
        for (int d = 1; d < 64; d <<= 1) {
            unsigned t = __shfl_up(pre, d, 64);
            if (tid >= d) pre += t;
        }
        unsigned ex = pre - tot;                 // exclusive prefix
        bst[4 * tid + 0] = ex;
        bst[4 * tid + 1] = ex + s0;
        bst[4 * tid + 2] = ex + s0 + s1;
        bst[4 * tid + 3] = ex + s0 + s1 + s2;
        if (tid == 63) bst[NBINS] = ex + tot;    // == NPTS
    }
    __syncthreads();

    hist[tid] = bst[tid];                        // running scatter offsets
    __syncthreads();

#pragma unroll
    for (int k = 0; k < 16; ++k) {
        unsigned pos = atomicAdd(&hist[pb[k]], 1u);
        wsPts[(size_t)b * NPTS + pos] =
            make_float4(px[k], py[k], pz[k], __uint_as_float((unsigned)pidx[k]));
    }
    wsBins[b * (NBINS + 1) + tid] = bst[tid];
    if (tid == 0) wsBins[b * (NBINS + 1) + NBINS] = bst[NBINS];
}

// ---- kernel 2: windowed kNN scan + PCA normal + loss ----
__device__ __forceinline__ int findbin(const unsigned int* bst, int j) {
    int lo = 0, hi = NBINS - 1;
#pragma unroll
    for (int it = 0; it < 8; ++it) {
        int mid = (lo + hi + 1) >> 1;
        if ((int)bst[mid] <= j) lo = mid; else hi = mid - 1;
    }
    return lo;
}

#define SIFT_CAND(J)                                                        \
    {                                                                       \
        float4 c = pts[(J)];                                                \
        float sw = q.w + c.w;                                               \
        float dp = fmaf(q.x, c.x, fmaf(q.y, c.y, q.z * c.z));               \
        float d  = fmaf(-2.0f, dp, sw);                                     \
        d = fmaxf(d, 0.0f);                                                 \
        unsigned int key = (__float_as_uint(d) & 0xFFFFF000u) | (unsigned)(J); \
        sift(nd, key);                                                      \
    }

__global__ __launch_bounds__(256) void gtnl_scan(
    const float4* __restrict__ wsPts, const unsigned int* __restrict__ wsBins,
    const float* __restrict__ gt, float* __restrict__ partial)
{
    __shared__ float4 pts[NPTS];                 // 64 KB binned batch (w = |p|^2)
    __shared__ unsigned int bst[NBINS + 1];
    __shared__ unsigned int mbuf[3][64][KNN];    // waves 1..3 partial lists

    const int tid  = threadIdx.x;
    const int bid  = blockIdx.x;
    const int b    = bid >> 6;                   // batch
    const int chunk= bid & 63;
    const int qbase= chunk * 64;
    const int w    = tid >> 6;                   // wave role
    const int lane = tid & 63;

    const float4* wp = wsPts + (size_t)b * NPTS;
    for (int p = tid; p < NPTS; p += 256) {
        float4 v = wp[p];
        pts[p] = make_float4(v.x, v.y, v.z, fmaf(v.x, v.x, fmaf(v.y, v.y, v.z * v.z)));
    }
    for (int i = tid; i < NBINS + 1; i += 256) bst[i] = wsBins[b * (NBINS + 1) + i];
    __syncthreads();

    const int qpos = qbase + lane;
    const float4 q = pts[qpos];

    unsigned int nd[KNN];
#pragma unroll
    for (int t = 0; t < KNN; ++t) nd[t] = 0x7F000000u;   // huge finite sentinel

    // warm-up: own 64-query chunk (includes self; dup-guarded at merge)
#pragma unroll 4
    for (int j = qbase; j < qbase + 64; ++j) SIFT_CAND(j)

    const int side   = w >> 1;                   // 0 = left, 1 = right
    const int parity = w & 1;

    if (side == 0) {
        if (qbase > 0) {
            int bb = findbin(bst, qbase - 1);
            while (bb >= 0) {
                if ((bb & 1) == parity) {
                    float hi  = XLO + (float)(bb + 1) * BINW;
                    float gap = fmaxf(q.x - hi, 0.0f);
                    float thr = __uint_as_float((nd[KNN - 1] & 0xFFFFF000u) + 0x1000u);
                    if (!__any(gap * gap < thr)) break;
                    int lo  = (int)bst[bb];
                    int hi2 = (int)bst[bb + 1]; hi2 = hi2 < qbase ? hi2 : qbase;
#pragma unroll 4
                    for (int j = lo; j < hi2; ++j) SIFT_CAND(j)
                }
                --bb;
            }
        }
    } else {
        if (qbase + 64 < NPTS) {
            int bb = findbin(bst, qbase + 64);
            while (bb < NBINS) {
                if ((bb & 1) == parity) {
                    float lox = XLO + (float)bb * BINW;
                    float gap = fmaxf(lox - q.x, 0.0f);
                    float thr = __uint_as_float((nd[KNN - 1] & 0xFFFFF000u) + 0x1000u);
                    if (!__any(gap * gap < thr)) break;
                    int lo  = (int)bst[bb]; lo = lo > qbase + 64 ? lo : qbase + 64;
                    int hi2 = (int)bst[bb + 1];
#pragma unroll 4
                    for (int j = lo; j < hi2; ++j) SIFT_CAND(j)
                }
                ++bb;
            }
        }
    }

    if (w != 0) {
#pragma unroll
        for (int t = 0; t < KNN; ++t) mbuf[w - 1][lane][t] = nd[t];
    }
    __syncthreads();

    if (w == 0) {
        // exact merge; guard duplicates (shared warm-up candidates)
#pragma unroll
        for (int s = 0; s < 3; ++s) {
#pragma unroll
            for (int t = 0; t < KNN; ++t) {
                unsigned int k = mbuf[s][lane][t];
                bool dup = (k == nd[0]) | (k == nd[1]) | (k == nd[2]) | (k == nd[3]) |
                           (k == nd[4]) | (k == nd[5]) | (k == nd[6]) | (k == nd[7]) |
                           (k == nd[8]) | (k == nd[9]);
                sift(nd, dup ? 0xFFFFFFFFu : k);
            }
        }

        unsigned int qorig = __float_as_uint(wp[qpos].w);
        float res = normal_loss(pts, nd, gt + ((size_t)b * NPTS + qorig) * 3);

#pragma unroll
        for (int d = 32; d > 0; d >>= 1) res += __shfl_xor(res, d, 64);
        if (lane == 0) partial[bid] = res;
    }
}

// ---- fallback: R2 brute force (used when ws_size is too small) ----
__global__ __launch_bounds__(256) void gtnl_brute(
    const float* __restrict__ pred, const float* __restrict__ gt,
    float* __restrict__ partial)
{
    __shared__ float4 pts[NPTS];
    __shared__ unsigned int mbuf[64][3][KNN];

    const int tid = threadIdx.x;
    const int b   = blockIdx.x >> 6;
    const int qc  = blockIdx.x & 63;
    const int ql  = tid & 63;
    const int sub = tid >> 6;
    const int qi  = qc * 64 + ql;

    const float* src = pred + (size_t)b * NPTS * 3;
    for (int p = tid; p < NPTS; p += 256) {
        float x = src[3 * p + 0], y = src[3 * p + 1], z = src[3 * p + 2];
        pts[p] = make_float4(x, y, z, fmaf(x, x, fmaf(y, y, z * z)));
    }
    __syncthreads();

    const float4 q = pts[qi];
    unsigned int nd[KNN];
#pragma unroll
    for (int t = 0; t < KNN; ++t) nd[t] = 0xFFFFFFFFu;

    const int j0 = sub * 1024;
#pragma unroll 8
    for (int j = j0; j < j0 + 1024; ++j) SIFT_CAND(j)

    if (sub != 0) {
#pragma unroll
        for (int t = 0; t < KNN; ++t) mbuf[ql][sub - 1][t] = nd[t];
    }
    __syncthreads();

    float res = 0.0f;
    if (sub == 0) {
#pragma unroll
        for (int s = 0; s < 3; ++s)
#pragma unroll
            for (int t = 0; t < KNN; ++t) sift(nd, mbuf[ql][s][t]);
        res = normal_loss(pts, nd, gt + ((size_t)b * NPTS + qi) * 3);
#pragma unroll
        for (int d = 32; d > 0; d >>= 1) res += __shfl_xor(res, d, 64);
    }
    __syncthreads();
    if (tid == 0) partial[blockIdx.x] = res;
}

__global__ __launch_bounds__(SCAN_BLOCKS) void gtnl_reduce(
    const float* __restrict__ partial, float* __restrict__ out)
{
    __shared__ float s[SCAN_BLOCKS];
    const int tid = threadIdx.x;
    s[tid] = partial[tid];
    __syncthreads();
    for (int k = SCAN_BLOCKS / 2; k > 0; k >>= 1) {
        if (tid < k) s[tid] += s[tid + k];
        __syncthreads();
    }
    if (tid == 0) out[0] = s[0] / 32768.0f;
}

extern "C" void kernel_launch(void* const* d_in, const int* in_sizes, int n_in,
                              void* d_out, int out_size, void* d_ws, size_t ws_size,
                              hipStream_t stream) {
    const float* pred = (const float*)d_in[0];
    const float* gt   = (const float*)d_in[1];
    float* out        = (float*)d_out;

    const size_t PTS_BYTES  = (size_t)8 * NPTS * sizeof(float4);        // 524288
    const size_t BINS_BYTES = (size_t)8 * (NBINS + 1) * sizeof(unsigned); // 8224
    const size_t PART_BYTES = (size_t)SCAN_BLOCKS * sizeof(float);       // 2048

    if (ws_size >= PTS_BYTES + BINS_BYTES + PART_BYTES) {
        float4*       wsPts  = (float4*)d_ws;
        unsigned int* wsBins = (unsigned int*)((char*)d_ws + PTS_BYTES);
        float*        partial= (float*)((char*)d_ws + PTS_BYTES + BINS_BYTES);

        gtnl_bin<<<8, 256, 0, stream>>>(pred, wsPts, wsBins);
        gtnl_scan<<<SCAN_BLOCKS, 256, 0, stream>>>(wsPts, wsBins, gt, partial);
        gtnl_reduce<<<1, SCAN_BLOCKS, 0, stream>>>(partial, out);
    } else {
        float* partial = (float*)d_ws;   // 512 floats
        gtnl_brute<<<SCAN_BLOCKS, 256, 0, stream>>>(pred, gt, partial);
        gtnl_reduce<<<1, SCAN_BLOCKS, 0, stream>>>(partial, out);
    }
}

// Round 4
// 93.976 us; speedup vs baseline: 1.5853x; 1.5853x over previous
//
#include <hip/hip_runtime.h>
#include <math.h>

// GTNormalLoss: kNN(k=10) PCA normals + cosine loss vs gt, mean over 8x4096 points.
// Round 4: x-sorted (256-bin counting sort) + two-phase exact pruning with
// FIXED-SHAPE unrolled loops (R3's dynamic per-bin loops were latency-bound).
// Phase 1: 512-pt slab around query chunk, stride-4 across waves -> exact slab
// top-10 -> upper bound thr >= true d10. Phase 2: one wave-common window
// [Jlo,Jhi) from bin table, scan window\slab stride-4 with sentinel-guarded
// unroll. Disjoint merge -> exact global top-10.

#define NPTS    4096
#define KNN     10
#define NBINS   256
#define XLO     (-5.5f)
#define BINW    (11.0f / 256.0f)
#define INVBW   (256.0f / 11.0f)
#define SLAB    512
#define SCAN_BLOCKS 512          // 8 batches * 64 chunks of 64 queries

__device__ __forceinline__ unsigned int umed3(unsigned int a, unsigned int b, unsigned int c) {
    unsigned int r;
    asm("v_med3_u32 %0, %1, %2, %3" : "=v"(r) : "v"(a), "v"(b), "v"(c));
    return r;
}

// insert key into ascending sorted nd[0..9], dropping old max; all static indexing.
__device__ __forceinline__ void sift(unsigned int nd[KNN], unsigned int key) {
#pragma unroll
    for (int t = KNN - 1; t >= 1; --t)
        nd[t] = umed3(key, nd[t - 1], nd[t]);
    nd[0] = nd[0] < key ? nd[0] : key;
}

__device__ __forceinline__ int xbin(float x) {
    int bin = (int)floorf((x - XLO) * INVBW);
    return bin < 0 ? 0 : (bin > NBINS - 1 ? NBINS - 1 : bin);
}

// ---- shared epilogue: covariance -> smallest eigenvector -> 1-cos loss ----
__device__ float normal_loss(const float4* pts, const unsigned int nd[KNN],
                             const float* g3)
{
    float nbx[KNN], nby[KNN], nbz[KNN];
    float sx = 0.f, sy = 0.f, sz = 0.f;
#pragma unroll
    for (int t = 0; t < KNN; ++t) {
        float4 pn = pts[nd[t] & 0xFFFu];
        nbx[t] = pn.x; nby[t] = pn.y; nbz[t] = pn.z;
        sx += pn.x; sy += pn.y; sz += pn.z;
    }
    float mx = sx / 10.0f, my = sy / 10.0f, mz = sz / 10.0f;
    float c00 = 0.f, c01 = 0.f, c02 = 0.f, c11 = 0.f, c12 = 0.f, c22 = 0.f;
#pragma unroll
    for (int t = 0; t < KNN; ++t) {
        float ux = nbx[t] - mx, uy = nby[t] - my, uz = nbz[t] - mz;
        c00 = fmaf(ux, ux, c00);
        c01 = fmaf(ux, uy, c01);
        c02 = fmaf(ux, uz, c02);
        c11 = fmaf(uy, uy, c11);
        c12 = fmaf(uy, uz, c12);
        c22 = fmaf(uz, uz, c22);
    }
    double a00 = (double)(c00 / 10.0f), a01 = (double)(c01 / 10.0f);
    double a02 = (double)(c02 / 10.0f), a11 = (double)(c11 / 10.0f);
    double a12 = (double)(c12 / 10.0f), a22 = (double)(c22 / 10.0f);

    double vx = 1.0, vy = 0.0, vz = 0.0;
    double qd = (a00 + a11 + a22) / 3.0;
    double p1 = a01 * a01 + a02 * a02 + a12 * a12;
    double b00 = a00 - qd, b11 = a11 - qd, b22 = a22 - qd;
    double p2 = b00 * b00 + b11 * b11 + b22 * b22 + 2.0 * p1;
    if (p2 > 1e-300) {
        double p = sqrt(p2 / 6.0);
        double inv = 1.0 / p;
        double m00 = b00 * inv, m01 = a01 * inv, m02 = a02 * inv;
        double m11 = b11 * inv, m12 = a12 * inv, m22 = b22 * inv;
        double detB = m00 * (m11 * m22 - m12 * m12)
                    - m01 * (m01 * m22 - m12 * m02)
                    + m02 * (m01 * m12 - m11 * m02);
        double r = 0.5 * detB;
        r = r < -1.0 ? -1.0 : (r > 1.0 ? 1.0 : r);
        double phi = acos(r) / 3.0;
        double eig0 = qd + 2.0 * p * cos(phi + 2.0943951023931953); // smallest
        double r0x = a00 - eig0, r0y = a01, r0z = a02;
        double r1y = a11 - eig0, r1z = a12;
        double r2z = a22 - eig0;
        double c0x = r0y * r1z - r0z * r1y;
        double c0y = r0z * r0y - r0x * r1z;
        double c0z = r0x * r1y - r0y * r0y;
        double c1x = r0y * r2z - r0z * r1z;
        double c1y = r0z * r0z - r0x * r2z;
        double c1z = r0x * r1z - r0y * r0z;
        double c2x = r1y * r2z - r1z * r1z;
        double c2y = r1z * r0z - r0y * r2z;
        double c2z = r0y * r1z - r1y * r0z;
        double n0 = c0x * c0x + c0y * c0y + c0z * c0z;
        double n1 = c1x * c1x + c1y * c1y + c1z * c1z;
        double n2 = c2x * c2x + c2y * c2y + c2z * c2z;
        double bx, by, bz, bn;
        if (n0 >= n1 && n0 >= n2) { bx = c0x; by = c0y; bz = c0z; bn = n0; }
        else if (n1 >= n2)        { bx = c1x; by = c1y; bz = c1z; bn = n1; }
        else                      { bx = c2x; by = c2y; bz = c2z; bn = n2; }
        if (bn > 1e-300) {
            double s = 1.0 / sqrt(bn);
            vx = bx * s; vy = by * s; vz = bz * s;
        }
    }
    float nx = (float)vx, ny = (float)vy, nz = (float)vz;
    float gx = g3[0], gy = g3[1], gz = g3[2];
    float dotg = nx * gx + ny * gy + nz * gz;
    float na = sqrtf(nx * nx + ny * ny + nz * nz);
    float gn = sqrtf(gx * gx + gy * gy + gz * gz);
    float cs = dotg / (fmaxf(na, 1e-8f) * fmaxf(gn, 1e-8f));
    return 1.0f - cs;
}

// ---- kernel 1: counting-sort each batch's points into 256 x-bins ----
__global__ __launch_bounds__(256) void gtnl_bin(
    const float* __restrict__ pred, float4* __restrict__ wsPts,
    unsigned int* __restrict__ wsBins)
{
    __shared__ unsigned int hist[NBINS];
    __shared__ unsigned int bst[NBINS + 1];

    const int tid = threadIdx.x;
    const int b   = blockIdx.x;
    const float* src = pred + (size_t)b * NPTS * 3;

    hist[tid] = 0;
    __syncthreads();

    float px[16], py[16], pz[16];
    int   pb[16], pidx[16];
#pragma unroll
    for (int k = 0; k < 16; ++k) {
        int p = tid + 256 * k;
        float x = src[3 * p + 0];
        float y = src[3 * p + 1];
        float z = src[3 * p + 2];
        int bin = xbin(x);
        px[k] = x; py[k] = y; pz[k] = z; pb[k] = bin; pidx[k] = p;
        atomicAdd(&hist[bin], 1u);
    }
    __syncthreads();

    if (tid < 64) {
        unsigned s0 = hist[4 * tid + 0], s1 = hist[4 * tid + 1];
        unsigned s2 = hist[4 * tid + 2], s3 = hist[4 * tid + 3];
        unsigned tot = s0 + s1 + s2 + s3;
        unsigned pre = tot;
#pragma unroll
        for (int d = 1; d < 64; d <<= 1) {
            unsigned t = __shfl_up(pre, d, 64);
            if (tid >= d) pre += t;
        }
        unsigned ex = pre - tot;                 // exclusive prefix
        bst[4 * tid + 0] = ex;
        bst[4 * tid + 1] = ex + s0;
        bst[4 * tid + 2] = ex + s0 + s1;
        bst[4 * tid + 3] = ex + s0 + s1 + s2;
        if (tid == 63) bst[NBINS] = ex + tot;    // == NPTS
    }
    __syncthreads();

    hist[tid] = bst[tid];                        // running scatter offsets
    __syncthreads();

#pragma unroll
    for (int k = 0; k < 16; ++k) {
        unsigned pos = atomicAdd(&hist[pb[k]], 1u);
        wsPts[(size_t)b * NPTS + pos] =
            make_float4(px[k], py[k], pz[k], __uint_as_float((unsigned)pidx[k]));
    }
    wsBins[b * (NBINS + 1) + tid] = bst[tid];
    if (tid == 0) wsBins[b * (NBINS + 1) + NBINS] = bst[NBINS];
}

#define SIFT_CAND(J)                                                        \
    {                                                                       \
        float4 c = pts[(J)];                                                \
        float sw = q.w + c.w;                                               \
        float dp = fmaf(q.x, c.x, fmaf(q.y, c.y, q.z * c.z));               \
        float d  = fmaf(-2.0f, dp, sw);                                     \
        d = fmaxf(d, 0.0f);                                                 \
        unsigned int key = (__float_as_uint(d) & 0xFFFFF000u) | (unsigned)(J); \
        sift(nd, key);                                                      \
    }

// ---- kernel 2: two-phase exact windowed kNN + PCA normal + loss ----
__global__ __launch_bounds__(256) void gtnl_scan(
    const float4* __restrict__ wsPts, const unsigned int* __restrict__ wsBins,
    const float* __restrict__ gt, float* __restrict__ partial)
{
    __shared__ float4 pts[NPTS];                 // 64 KB binned batch (w = |p|^2)
    __shared__ unsigned int bst[NBINS + 1];
    __shared__ unsigned int mbuf[4][64][KNN];    // per-wave partial lists

    const int tid  = threadIdx.x;
    const int bid  = blockIdx.x;
    const int b    = bid >> 6;                   // batch
    const int chunk= bid & 63;
    const int qbase= chunk * 64;
    const int w    = tid >> 6;                   // wave role 0..3
    const int lane = tid & 63;

    const float4* wp = wsPts + (size_t)b * NPTS;
    for (int p = tid; p < NPTS; p += 256) {
        float4 v = wp[p];
        pts[p] = make_float4(v.x, v.y, v.z, fmaf(v.x, v.x, fmaf(v.y, v.y, v.z * v.z)));
    }
    for (int i = tid; i < NBINS + 1; i += 256) bst[i] = wsBins[b * (NBINS + 1) + i];
    __syncthreads();

    const int qpos = qbase + lane;
    const float4 q = pts[qpos];

    // ---- phase 1: 512-pt slab centered on chunk, stride-4 across waves ----
    int W0 = qbase + 32 - SLAB / 2;
    W0 = W0 < 0 ? 0 : (W0 > NPTS - SLAB ? NPTS - SLAB : W0);

    unsigned int nd[KNN];
#pragma unroll
    for (int t = 0; t < KNN; ++t) nd[t] = 0x7F000000u;   // huge finite sentinel

#pragma unroll 8
    for (int t = 0; t < SLAB / 4; ++t) {
        int j = W0 + 4 * t + w;
        SIFT_CAND(j)
    }

    // publish and merge -> exact slab top-10 (identical in every wave)
#pragma unroll
    for (int t = 0; t < KNN; ++t) mbuf[w][lane][t] = nd[t];
    __syncthreads();
#pragma unroll
    for (int s = 0; s < 4; ++s) {
        if (s != w) {
#pragma unroll
            for (int t = 0; t < KNN; ++t) sift(nd, mbuf[s][lane][t]);
        }
    }

    // conservative upper bound on true d10 (+truncation slack, +sqrt slack)
    unsigned int thr_bits = (nd[KNN - 1] & 0xFFFFF000u) + 0x1000u;
    float thr = __uint_as_float(thr_bits);
    float hw  = __uint_as_float(__float_as_uint(sqrtf(thr)) + 2);

    // wave-common window [Jlo, Jhi) from bin table
    int jlo = (int)bst[xbin(q.x - hw)];
    int jhi = (int)bst[xbin(q.x + hw) + 1];
#pragma unroll
    for (int d = 32; d > 0; d >>= 1) {
        int tlo = __shfl_xor(jlo, d, 64);
        int thi = __shfl_xor(jhi, d, 64);
        jlo = jlo < tlo ? jlo : tlo;
        jhi = jhi > thi ? jhi : thi;
    }

    const int L     = (W0 - jlo) > 0 ? (W0 - jlo) : 0;       // left remainder
    const int Rs    = W0 + SLAB;
    const int R     = (jhi - Rs) > 0 ? (jhi - Rs) : 0;       // right remainder
    const int total = L + R;

    __syncthreads();      // all phase-1 mbuf reads done before reuse

    // waves 1..3 restart with fresh lists (their phase-2 shares are disjoint
    // from the slab); wave 0 keeps the slab top-10 as its base.
    if (w != 0) {
#pragma unroll
        for (int t = 0; t < KNN; ++t) nd[t] = 0xFFFFFFFFu;
    }

    // ---- phase 2: scan window \ slab, stride-4, sentinel-guarded unroll ----
    for (int v = w; v < total; v += 16) {
#pragma unroll
        for (int u = 0; u < 4; ++u) {
            int vv = v + 4 * u;
            int j  = vv < L ? jlo + vv : Rs + (vv - L);
            j = vv < total ? j : jlo;                    // safe address
            float4 c = pts[j];
            float sw = q.w + c.w;
            float dp = fmaf(q.x, c.x, fmaf(q.y, c.y, q.z * c.z));
            float d  = fmaf(-2.0f, dp, sw);
            d = fmaxf(d, 0.0f);
            unsigned int key = (__float_as_uint(d) & 0xFFFFF000u) | (unsigned)j;
            key = vv < total ? key : 0xFFFFFFFFu;        // OOB -> inert sentinel
            sift(nd, key);
        }
    }

    if (w != 0) {
#pragma unroll
        for (int t = 0; t < KNN; ++t) mbuf[w][lane][t] = nd[t];
    }
    __syncthreads();

    if (w == 0) {
        // disjoint merge: slab ∪ share0 (in nd) ∪ share1..3
#pragma unroll
        for (int s = 1; s < 4; ++s)
#pragma unroll
            for (int t = 0; t < KNN; ++t) sift(nd, mbuf[s][lane][t]);

        unsigned int qorig = __float_as_uint(wp[qpos].w);
        float res = normal_loss(pts, nd, gt + ((size_t)b * NPTS + qorig) * 3);

#pragma unroll
        for (int d = 32; d > 0; d >>= 1) res += __shfl_xor(res, d, 64);
        if (lane == 0) partial[bid] = res;
    }
}

// ---- fallback: R2 brute force (used when ws_size is too small) ----
__global__ __launch_bounds__(256) void gtnl_brute(
    const float* __restrict__ pred, const float* __restrict__ gt,
    float* __restrict__ partial)
{
    __shared__ float4 pts[NPTS];
    __shared__ unsigned int mbuf[64][3][KNN];

    const int tid = threadIdx.x;
    const int b   = blockIdx.x >> 6;
    const int qc  = blockIdx.x & 63;
    const int ql  = tid & 63;
    const int sub = tid >> 6;
    const int qi  = qc * 64 + ql;

    const float* src = pred + (size_t)b * NPTS * 3;
    for (int p = tid; p < NPTS; p += 256) {
        float x = src[3 * p + 0], y = src[3 * p + 1], z = src[3 * p + 2];
        pts[p] = make_float4(x, y, z, fmaf(x, x, fmaf(y, y, z * z)));
    }
    __syncthreads();

    const float4 q = pts[qi];
    unsigned int nd[KNN];
#pragma unroll
    for (int t = 0; t < KNN; ++t) nd[t] = 0xFFFFFFFFu;

    const int j0 = sub * 1024;
#pragma unroll 8
    for (int j = j0; j < j0 + 1024; ++j) SIFT_CAND(j)

    if (sub != 0) {
#pragma unroll
        for (int t = 0; t < KNN; ++t) mbuf[ql][sub - 1][t] = nd[t];
    }
    __syncthreads();

    float res = 0.0f;
    if (sub == 0) {
#pragma unroll
        for (int s = 0; s < 3; ++s)
#pragma unroll
            for (int t = 0; t < KNN; ++t) sift(nd, mbuf[ql][s][t]);
        res = normal_loss(pts, nd, gt + ((size_t)b * NPTS + qi) * 3);
#pragma unroll
        for (int d = 32; d > 0; d >>= 1) res += __shfl_xor(res, d, 64);
    }
    __syncthreads();
    if (tid == 0) partial[blockIdx.x] = res;
}

__global__ __launch_bounds__(SCAN_BLOCKS) void gtnl_reduce(
    const float* __restrict__ partial, float* __restrict__ out)
{
    __shared__ float s[SCAN_BLOCKS];
    const int tid = threadIdx.x;
    s[tid] = partial[tid];
    __syncthreads();
    for (int k = SCAN_BLOCKS / 2; k > 0; k >>= 1) {
        if (tid < k) s[tid] += s[tid + k];
        __syncthreads();
    }
    if (tid == 0) out[0] = s[0] / 32768.0f;
}

extern "C" void kernel_launch(void* const* d_in, const int* in_sizes, int n_in,
                              void* d_out, int out_size, void* d_ws, size_t ws_size,
                              hipStream_t stream) {
    const float* pred = (const float*)d_in[0];
    const float* gt   = (const float*)d_in[1];
    float* out        = (float*)d_out;

    const size_t PTS_BYTES  = (size_t)8 * NPTS * sizeof(float4);          // 524288
    const size_t BINS_BYTES = (size_t)8 * (NBINS + 1) * sizeof(unsigned); // 8224
    const size_t PART_BYTES = (size_t)SCAN_BLOCKS * sizeof(float);        // 2048

    if (ws_size >= PTS_BYTES + BINS_BYTES + PART_BYTES) {
        float4*       wsPts  = (float4*)d_ws;
        unsigned int* wsBins = (unsigned int*)((char*)d_ws + PTS_BYTES);
        float*        partial= (float*)((char*)d_ws + PTS_BYTES + BINS_BYTES);

        gtnl_bin<<<8, 256, 0, stream>>>(pred, wsPts, wsBins);
        gtnl_scan<<<SCAN_BLOCKS, 256, 0, stream>>>(wsPts, wsBins, gt, partial);
        gtnl_reduce<<<1, SCAN_BLOCKS, 0, stream>>>(partial, out);
    } else {
        float* partial = (float*)d_ws;   // 512 floats
        gtnl_brute<<<SCAN_BLOCKS, 256, 0, stream>>>(pred, gt, partial);
        gtnl_reduce<<<1, SCAN_BLOCKS, 0, stream>>>(partial, out);
    }
}